// Round 2
// baseline (669.103 us; speedup 1.0000x reference)
//
#include <hip/hip_runtime.h>
#include <cstdint>
#include <cstddef>

#define BSZ 2
#define NV 16
#define SEQ 1024
#define DIM 768
#define VOC 50257
#define VOCP 50304   // padded to multiple of 128

typedef unsigned int u32;
typedef unsigned short u16;
typedef _Float16 half8 __attribute__((ext_vector_type(8)));
typedef float f32x4 __attribute__((ext_vector_type(4)));

__device__ __forceinline__ u16 f2h(float f) {
  return __builtin_bit_cast(unsigned short, (_Float16)f);
}
__device__ __forceinline__ u32 pk2h(float a, float b) {
  return (u32)f2h(a) | ((u32)f2h(b) << 16);
}

// async global->LDS, 16B per lane; LDS dest = wave-uniform base + lane*16
__device__ __forceinline__ void gload16(const u16* g, u16* l) {
  __builtin_amdgcn_global_load_lds(
      (const __attribute__((address_space(1))) void*)g,
      (__attribute__((address_space(3))) void*)l, 16, 0, 0);
}

// ---------------------------------------------------------------------------
// K1: content f32 -> f16 (normal + transposed per (b,k) slice)
// grid (DIM/32, SEQ/32, BSZ*NV), block (32,8)
__global__ void k_prep_content(const float* __restrict__ content,
                               u16* __restrict__ cbf, u16* __restrict__ cT) {
  __shared__ u16 tile[32][33];
  const int bk = blockIdx.z;
  const int d0 = blockIdx.x * 32, j0 = blockIdx.y * 32;
  const float* src = content + (size_t)bk * SEQ * DIM;
  u16* dst = cbf + (size_t)bk * SEQ * DIM;
  u16* dstT = cT + (size_t)bk * DIM * SEQ;
  const int c = threadIdx.x;
#pragma unroll
  for (int rr = 0; rr < 4; ++rr) {
    const int r = threadIdx.y * 4 + rr;
    const float v = src[(size_t)(j0 + r) * DIM + d0 + c];
    const u16 bv = f2h(v);
    dst[(size_t)(j0 + r) * DIM + d0 + c] = bv;
    tile[r][c] = bv;
  }
  __syncthreads();
#pragma unroll
  for (int rr = 0; rr < 4; ++rr) {
    const int r = threadIdx.y * 4 + rr;       // d-local
    dstT[(size_t)(d0 + r) * SEQ + j0 + c] = tile[c][r];
  }
}

// K2: lm_head_weight f32 -> f16, padded rows [VOC,VOCP) zeroed. grid VOCP, block 192
__global__ void k_prep_w(const float* __restrict__ W, u16* __restrict__ Wb) {
  const int v = blockIdx.x;
  const int c = threadIdx.x * 4;
  u32 lo, hi;
  if (v < VOC) {
    const float4 f = *(const float4*)(W + (size_t)v * DIM + c);
    lo = pk2h(f.x, f.y); hi = pk2h(f.z, f.w);
  } else {
    lo = 0u; hi = 0u;
  }
  *(uint2*)(Wb + (size_t)v * DIM + c) = make_uint2(lo, hi);
}

// K3: gather Wg[b][j][:] = Wb[ids[b][j]][:]  grid (SEQ, BSZ), block 192
__global__ void k_gather(const int* __restrict__ ids, const u16* __restrict__ Wb,
                         u16* __restrict__ Wg) {
  const int b = blockIdx.y, j = blockIdx.x;
  const int row = ids[b * SEQ + j];
  const int c = threadIdx.x * 4;
  *(uint2*)(Wg + ((size_t)b * SEQ + j) * DIM + c) =
      *(const uint2*)(Wb + (size_t)row * DIM + c);
}

__global__ void k_zero(float* __restrict__ p, int n) {
  const int i = blockIdx.x * 256 + threadIdx.x;
  if (i < n) p[i] = 0.f;
}

// ---------------------------------------------------------------------------
// Shared 128x128-tile MFMA core (m97 structure). 256 threads = 4 waves (2x2),
// each wave 64x64 (4x4 fragments of 16x16x32 f16). BK=32.
// Staging: global_load_lds dwordx4, linear LDS [128][32] u16 per operand.
// Contraction over the last (contiguous) dim: C[i][j] = sum_k A[i][k]*B[j][k].
template <int LDA, int LDB>
__device__ __forceinline__ void gemm_ktile(const u16* __restrict__ A,
                                           const u16* __restrict__ B, int ksteps,
                                           u16* As, u16* Bs, f32x4 (&acc)[4][4],
                                           int t) {
  const int lane = t & 63, w = t >> 6, wr = w >> 1, wc = w & 1;
  const int kl = (lane >> 4) * 8, rl = lane & 15; // fragment addressing
  const int srow = t >> 2;                        // staging row (0..63)
  const int scol = (t & 3) * 8;                   // staging col (u16 units)
  u16* lA = As + w * 512;                         // wave-uniform LDS base
  u16* lB = Bs + w * 512;
  const u16* ga = A + (size_t)srow * LDA + scol;
  const u16* gb = B + (size_t)srow * LDB + scol;
  for (int kt = 0; kt < ksteps; ++kt) {
    __syncthreads();   // previous iteration's fragment reads complete
    gload16(ga, lA);                          // rows 0..63
    gload16(ga + (size_t)64 * LDA, lA + 2048);// rows 64..127
    gload16(gb, lB);
    gload16(gb + (size_t)64 * LDB, lB + 2048);
    ga += 32; gb += 32;
    __syncthreads();   // staging landed (vmcnt drain at barrier)
    half8 af[4], bf[4];
#pragma unroll
    for (int m = 0; m < 4; ++m)
      af[m] = *(const half8*)(As + (wr * 64 + m * 16 + rl) * 32 + kl);
#pragma unroll
    for (int n = 0; n < 4; ++n)
      bf[n] = *(const half8*)(Bs + (wc * 64 + n * 16 + rl) * 32 + kl);
#pragma unroll
    for (int m = 0; m < 4; ++m)
#pragma unroll
      for (int n = 0; n < 4; ++n)
        acc[m][n] = __builtin_amdgcn_mfma_f32_16x16x32_f16(af[m], bf[n], acc[m][n], 0, 0, 0);
  }
}

// K4: sims[bk][i] += sum_j relu(content[bk] @ Wg[b]^T). grid (8,8,32)
__global__ __launch_bounds__(256) void k_sims(const u16* __restrict__ cbf,
                                              const u16* __restrict__ Wg,
                                              float* __restrict__ sims) {
  __shared__ __align__(16) u16 As[128 * 32];
  __shared__ __align__(16) u16 Bs[128 * 32];
  const int bk = blockIdx.z, b = bk >> 4;
  const int t = threadIdx.x;
  const u16* A = cbf + (size_t)bk * SEQ * DIM + (size_t)(blockIdx.y * 128) * DIM;
  const u16* B = Wg + (size_t)b * SEQ * DIM + (size_t)(blockIdx.x * 128) * DIM;
  f32x4 acc[4][4] = {};
  gemm_ktile<DIM, DIM>(A, B, DIM / 32, As, Bs, acc, t);
  const int lane = t & 63, w = t >> 6, wr = w >> 1;
  const int rg = lane >> 4, cl = lane & 15;
#pragma unroll
  for (int m = 0; m < 4; ++m) {
#pragma unroll
    for (int r = 0; r < 4; ++r) {
      float s = 0.f;
#pragma unroll
      for (int n = 0; n < 4; ++n) {
        const float v = acc[m][n][r];
        s += fmaxf(v, 0.f);
      }
      s += __shfl_xor(s, 1);
      s += __shfl_xor(s, 2);
      s += __shfl_xor(s, 4);
      s += __shfl_xor(s, 8);
      if (cl == 0) {
        const int i = blockIdx.y * 128 + wr * 64 + m * 16 + rg * 4 + r;
        atomicAdd(&sims[(size_t)bk * SEQ + i], s);
      }
    }
  }
}

// K5: wtsT[bk][j] = cw*score + (1-score). grid (4,32), block 256
__global__ void k_weights(const float* __restrict__ sims, const int* __restrict__ ids,
                          const float* __restrict__ cw, float* __restrict__ wtsT) {
  const int j = blockIdx.x * 256 + threadIdx.x;
  const int bk = blockIdx.y;
  const int b = bk >> 4, k = bk & 15;
  const float sm = sims[(size_t)bk * SEQ + j];
  float score = 1.f / (1.f + __expf(0.1f * sm - 6.f));  // sigmoid(-0.1*s + 6)
  score *= 1.f + (float)j * 0.01f;
  const int id = ids[b * SEQ + j];
  const float c = cw[(size_t)id * NV + k];
  wtsT[(size_t)bk * SEQ + j] = c * score + (1.f - score);
}

// K6: ctxw[bk][i][j] = f16(ctx * wtsT[bk][j]). grid 32768, block 256 (4 elems/thread)
__global__ void k_ctx(const float* __restrict__ ctx, const float* __restrict__ wtsT,
                      u16* __restrict__ ctxw) {
  const size_t i = ((size_t)blockIdx.x * 256 + threadIdx.x) * 4;
  const float4 c = *(const float4*)(ctx + i);
  const size_t bk = i >> 20;           // / (SEQ*SEQ)
  const int j = (int)(i & (SEQ - 1));  // column within row
  const float4 wv = *(const float4*)(wtsT + bk * SEQ + j);
  *(uint2*)(ctxw + i) =
      make_uint2(pk2h(c.x * wv.x, c.y * wv.y), pk2h(c.z * wv.z, c.w * wv.w));
}

// K7: hidden partials. grid (6, 8, 8): x=d-tile, y=i-tile, z=b*4+g (4 senses/group)
__global__ __launch_bounds__(256) void k_hidden(const u16* __restrict__ ctxw,
                                                const u16* __restrict__ cT,
                                                float* __restrict__ part) {
  __shared__ __align__(16) u16 As[128 * 32];
  __shared__ __align__(16) u16 Bs[128 * 32];
  const int z = blockIdx.z;
  const int b = z >> 2, g = z & 3;
  const int i0 = blockIdx.y * 128, d0 = blockIdx.x * 128;
  const int t = threadIdx.x;
  f32x4 acc[4][4] = {};
  for (int kk = 0; kk < 4; ++kk) {
    const int sense = g * 4 + kk;
    const u16* A = ctxw + ((size_t)(b * NV + sense) * SEQ + i0) * SEQ;
    const u16* B = cT + ((size_t)(b * NV + sense) * DIM + d0) * SEQ;
    gemm_ktile<SEQ, SEQ>(A, B, SEQ / 32, As, Bs, acc, t);
  }
  const int lane = t & 63, w = t >> 6, wr = w >> 1, wc = w & 1;
  const int rg = lane >> 4, cl = lane & 15;
  float* P = part + ((size_t)(g * BSZ + b) * SEQ + i0) * DIM + d0;
#pragma unroll
  for (int m = 0; m < 4; ++m)
#pragma unroll
    for (int n = 0; n < 4; ++n)
#pragma unroll
      for (int r = 0; r < 4; ++r)
        P[(size_t)(wr * 64 + m * 16 + rg * 4 + r) * DIM + wc * 64 + n * 16 + cl] =
            acc[m][n][r];
}

// K8: hid = f16(sum_g part[g]). grid 1536, block 256 (4 elems/thread)
__global__ void k_reduce(const float* __restrict__ part, u16* __restrict__ hid) {
  const size_t i = ((size_t)blockIdx.x * 256 + threadIdx.x) * 4;
  const size_t NHID = (size_t)BSZ * SEQ * DIM;
  float4 s = {0.f, 0.f, 0.f, 0.f};
#pragma unroll
  for (int g = 0; g < 4; ++g) {
    const float4 p = *(const float4*)(part + (size_t)g * NHID + i);
    s.x += p.x; s.y += p.y; s.z += p.z; s.w += p.w;
  }
  *(uint2*)(hid + i) = make_uint2(pk2h(s.x, s.y), pk2h(s.z, s.w));
}

// K9: logits = hid @ Wb^T. grid (16, 393): x=i-tile, y=v-tile
__global__ __launch_bounds__(256) void k_logits(const u16* __restrict__ hid,
                                                const u16* __restrict__ Wb,
                                                float* __restrict__ out) {
  __shared__ __align__(16) u16 As[128 * 32];
  __shared__ __align__(16) u16 Bs[128 * 32];
  const int i0 = blockIdx.x * 128, v0 = blockIdx.y * 128;
  const int t = threadIdx.x;
  const u16* A = hid + (size_t)i0 * DIM;
  const u16* B = Wb + (size_t)v0 * DIM;
  f32x4 acc[4][4] = {};
  gemm_ktile<DIM, DIM>(A, B, DIM / 32, As, Bs, acc, t);
  const int lane = t & 63, w = t >> 6, wr = w >> 1, wc = w & 1;
  const int rg = lane >> 4, cl = lane & 15;
#pragma unroll
  for (int m = 0; m < 4; ++m)
#pragma unroll
    for (int n = 0; n < 4; ++n) {
      const int vv = v0 + wc * 64 + n * 16 + cl;
      if (vv < VOC) {
#pragma unroll
        for (int r = 0; r < 4; ++r) {
          const int i = i0 + wr * 64 + m * 16 + rg * 4 + r;
          out[(size_t)i * VOC + vv] = acc[m][n][r];
        }
      }
    }
}

// ---------------------------------------------------------------------------
extern "C" void kernel_launch(void* const* d_in, const int* in_sizes, int n_in,
                              void* d_out, int out_size, void* d_ws, size_t ws_size,
                              hipStream_t stream) {
  const int* ids = (const int*)d_in[0];
  const float* content = (const float*)d_in[1];
  const float* ctx = (const float*)d_in[2];
  const float* W = (const float*)d_in[3];
  const float* cw = (const float*)d_in[4];
  float* out = (float*)d_out;
  char* ws = (char*)d_ws;

  // workspace layout (bytes, all 256-aligned); total 248,446,976
  u16* cbf  = (u16*)(ws);                  // 50,331,648  [32][S][D] f16
  u16* cT   = (u16*)(ws + 50331648);       // 50,331,648  [32][D][S] f16
  u16* Wb   = (u16*)(ws + 100663296);      // 77,266,944  [VOCP][D] f16
  u16* Wg   = (u16*)(ws + 177930240);      //  3,145,728  [B][S][D] f16
  u16* ctxw = (u16*)(ws + 181075968);      // 67,108,864  [32][S][S] f16
  float* sims = (float*)(ws + 248184832);  //    131,072  [32][S] f32
  float* wtsT = (float*)(ws + 248315904);  //    131,072  [32][S] f32
  // aliases (safe by dataflow: source buffer dead before alias first written)
  float* part = (float*)cbf;               // 25,165,824  [4][B][S][D] f32
  u16* hid = Wg;                           //  3,145,728  [B*S][D] f16

  k_prep_content<<<dim3(DIM / 32, SEQ / 32, BSZ * NV), dim3(32, 8), 0, stream>>>(
      content, cbf, cT);
  k_prep_w<<<VOCP, 192, 0, stream>>>(W, Wb);
  k_gather<<<dim3(SEQ, BSZ), 192, 0, stream>>>(ids, Wb, Wg);
  k_zero<<<128, 256, 0, stream>>>(sims, BSZ * NV * SEQ);
  k_sims<<<dim3(8, 8, BSZ * NV), 256, 0, stream>>>(cbf, Wg, sims);
  k_weights<<<dim3(4, BSZ * NV), 256, 0, stream>>>(sims, ids, cw, wtsT);
  k_ctx<<<32768, 256, 0, stream>>>(ctx, wtsT, ctxw);
  k_hidden<<<dim3(6, 8, 8), 256, 0, stream>>>(ctxw, cT, part);
  k_reduce<<<1536, 256, 0, stream>>>(part, hid);
  k_logits<<<dim3(16, 393), 256, 0, stream>>>(hid, Wb, out);
}

// Round 3
// 634.462 us; speedup vs baseline: 1.0546x; 1.0546x over previous
//
#include <hip/hip_runtime.h>
#include <cstdint>
#include <cstddef>

#define BSZ 2
#define NV 16
#define SEQ 1024
#define DIM 768
#define VOC 50257
#define VOCP 50304   // padded to multiple of 128

typedef unsigned int u32;
typedef unsigned short u16;
typedef _Float16 half8 __attribute__((ext_vector_type(8)));
typedef float f32x4 __attribute__((ext_vector_type(4)));

__device__ __forceinline__ u16 f2h(float f) {
  return __builtin_bit_cast(unsigned short, (_Float16)f);
}
__device__ __forceinline__ u32 pk2h(float a, float b) {
  return (u32)f2h(a) | ((u32)f2h(b) << 16);
}

// async global->LDS, 16B per lane; LDS dest = wave-uniform base + lane*16
__device__ __forceinline__ void gload16(const u16* g, u16* l) {
  __builtin_amdgcn_global_load_lds(
      (const __attribute__((address_space(1))) void*)g,
      (__attribute__((address_space(3))) void*)l, 16, 0, 0);
}

// ---------------------------------------------------------------------------
// K1: content f32 -> f16 (normal + transposed per (b,k) slice)
__global__ void k_prep_content(const float* __restrict__ content,
                               u16* __restrict__ cbf, u16* __restrict__ cT) {
  __shared__ u16 tile[32][33];
  const int bk = blockIdx.z;
  const int d0 = blockIdx.x * 32, j0 = blockIdx.y * 32;
  const float* src = content + (size_t)bk * SEQ * DIM;
  u16* dst = cbf + (size_t)bk * SEQ * DIM;
  u16* dstT = cT + (size_t)bk * DIM * SEQ;
  const int c = threadIdx.x;
#pragma unroll
  for (int rr = 0; rr < 4; ++rr) {
    const int r = threadIdx.y * 4 + rr;
    const float v = src[(size_t)(j0 + r) * DIM + d0 + c];
    const u16 bv = f2h(v);
    dst[(size_t)(j0 + r) * DIM + d0 + c] = bv;
    tile[r][c] = bv;
  }
  __syncthreads();
#pragma unroll
  for (int rr = 0; rr < 4; ++rr) {
    const int r = threadIdx.y * 4 + rr;       // d-local
    dstT[(size_t)(d0 + r) * SEQ + j0 + c] = tile[c][r];
  }
}

// K2: lm_head_weight f32 -> f16, padded rows zeroed. grid VOCP, block 192
__global__ void k_prep_w(const float* __restrict__ W, u16* __restrict__ Wb) {
  const int v = blockIdx.x;
  const int c = threadIdx.x * 4;
  u32 lo, hi;
  if (v < VOC) {
    const float4 f = *(const float4*)(W + (size_t)v * DIM + c);
    lo = pk2h(f.x, f.y); hi = pk2h(f.z, f.w);
  } else {
    lo = 0u; hi = 0u;
  }
  *(uint2*)(Wb + (size_t)v * DIM + c) = make_uint2(lo, hi);
}

// K3: gather Wg[b][j][:] = Wb[ids[b][j]][:]  grid (SEQ, BSZ), block 192
__global__ void k_gather(const int* __restrict__ ids, const u16* __restrict__ Wb,
                         u16* __restrict__ Wg) {
  const int b = blockIdx.y, j = blockIdx.x;
  const int row = ids[b * SEQ + j];
  const int c = threadIdx.x * 4;
  *(uint2*)(Wg + ((size_t)b * SEQ + j) * DIM + c) =
      *(const uint2*)(Wb + (size_t)row * DIM + c);
}

__global__ void k_zero(float* __restrict__ p, int n) {
  const int i = blockIdx.x * 256 + threadIdx.x;
  if (i < n) p[i] = 0.f;
}

// ---------------------------------------------------------------------------
// Shared 128x128 MFMA core, min-2-phase double-buffered (T3 recipe):
//   prologue STAGE(buf0); barrier;
//   loop: STAGE(buf^1, t+1); ds_read frags buf[cur]; MFMA; barrier; cur^=1;
//   tail: ds_read + MFMA on last buf (no trailing barrier; safe: next call's
//   prologue stages buf0, tail reads buf[(ksteps-1)&1]=buf1 for even ksteps).
// LDS linear [128][32] u16 per buffer; bank-conflict fix via 16B-granule XOR
// swizzle applied on BOTH the staged global source column and the fragment
// read address (involution, rule #21): granule ^= (row>>1)&3.
// C[i][j] = sum_k A[i][k]*B[j][k], contraction over contiguous dim.
template <int LDA, int LDB>
__device__ __forceinline__ void gemm_core(const u16* __restrict__ A,
                                          const u16* __restrict__ B, int ksteps,
                                          u16* As, u16* Bs, f32x4 (&acc)[4][4],
                                          int t) {
  const int lane = t & 63, w = t >> 6, wr = w >> 1, wc = w & 1;
  const int rl = lane & 15;
  const int gsw = (((lane >> 4) ^ ((rl >> 1) & 3)) * 8);  // read granule (u16)
  const int srow = 16 * w + (lane >> 2);                  // staging row 0..63
  const int sg = (((lane & 3) ^ ((lane >> 3) & 3)) * 8);  // staged src granule
  const size_t gaBase = (size_t)srow * LDA + sg;
  const size_t gbBase = (size_t)srow * LDB + sg;
  u16* lA = As + w * 512;  // wave-uniform LDS base (+bb*4096)
  u16* lB = Bs + w * 512;

#define STAGE_(bb, kt)                                                  \
  {                                                                     \
    const u16* ga_ = A + gaBase + (size_t)(kt) * 32;                    \
    const u16* gb_ = B + gbBase + (size_t)(kt) * 32;                    \
    gload16(ga_, lA + (bb) * 4096);                                     \
    gload16(ga_ + (size_t)64 * LDA, lA + (bb) * 4096 + 2048);           \
    gload16(gb_, lB + (bb) * 4096);                                     \
    gload16(gb_ + (size_t)64 * LDB, lB + (bb) * 4096 + 2048);           \
  }

#define FRAGS_(bb)                                                      \
  half8 af[4], bf[4];                                                   \
  _Pragma("unroll") for (int m = 0; m < 4; ++m)                         \
      af[m] = *(const half8*)(As + (bb) * 4096 +                        \
                              (wr * 64 + m * 16 + rl) * 32 + gsw);      \
  _Pragma("unroll") for (int n = 0; n < 4; ++n)                         \
      bf[n] = *(const half8*)(Bs + (bb) * 4096 +                        \
                              (wc * 64 + n * 16 + rl) * 32 + gsw);      \
  _Pragma("unroll") for (int m = 0; m < 4; ++m)                         \
      _Pragma("unroll") for (int n = 0; n < 4; ++n)                     \
          acc[m][n] = __builtin_amdgcn_mfma_f32_16x16x32_f16(           \
              af[m], bf[n], acc[m][n], 0, 0, 0);

  STAGE_(0, 0);
  __syncthreads();          // drains vmcnt: buf0 ready
  int cur = 0;
  for (int kt = 0; kt < ksteps - 1; ++kt) {
    STAGE_(cur ^ 1, kt + 1);  // issue next tile early; latency hides under MFMA
    { FRAGS_(cur); }
    __syncthreads();          // drains vmcnt (staged tile) + lgkm
    cur ^= 1;
  }
  { FRAGS_(cur); }            // tail, no barrier
#undef STAGE_
#undef FRAGS_
}

// K4: sims[bk][i] += sum_j relu(content[bk] @ Wg[b]^T). grid (8,8,32)
__global__ __launch_bounds__(256) void k_sims(const u16* __restrict__ cbf,
                                              const u16* __restrict__ Wg,
                                              float* __restrict__ sims) {
  __shared__ __align__(16) u16 As[2 * 128 * 32];
  __shared__ __align__(16) u16 Bs[2 * 128 * 32];
  const int bk = blockIdx.z, b = bk >> 4;
  const int t = threadIdx.x;
  const u16* A = cbf + (size_t)bk * SEQ * DIM + (size_t)(blockIdx.y * 128) * DIM;
  const u16* B = Wg + (size_t)b * SEQ * DIM + (size_t)(blockIdx.x * 128) * DIM;
  f32x4 acc[4][4] = {};
  gemm_core<DIM, DIM>(A, B, DIM / 32, As, Bs, acc, t);
  const int lane = t & 63, w = t >> 6, wr = w >> 1;
  const int rg = lane >> 4, cl = lane & 15;
#pragma unroll
  for (int m = 0; m < 4; ++m) {
#pragma unroll
    for (int r = 0; r < 4; ++r) {
      float s = 0.f;
#pragma unroll
      for (int n = 0; n < 4; ++n) {
        const float v = acc[m][n][r];
        s += fmaxf(v, 0.f);
      }
      s += __shfl_xor(s, 1);
      s += __shfl_xor(s, 2);
      s += __shfl_xor(s, 4);
      s += __shfl_xor(s, 8);
      if (cl == 0) {
        const int i = blockIdx.y * 128 + wr * 64 + m * 16 + rg * 4 + r;
        atomicAdd(&sims[(size_t)bk * SEQ + i], s);
      }
    }
  }
}

// K5: wtsT[bk][j] = cw*score + (1-score). grid (4,32), block 256
__global__ void k_weights(const float* __restrict__ sims, const int* __restrict__ ids,
                          const float* __restrict__ cw, float* __restrict__ wtsT) {
  const int j = blockIdx.x * 256 + threadIdx.x;
  const int bk = blockIdx.y;
  const int b = bk >> 4, k = bk & 15;
  const float sm = sims[(size_t)bk * SEQ + j];
  float score = 1.f / (1.f + __expf(0.1f * sm - 6.f));  // sigmoid(-0.1*s + 6)
  score *= 1.f + (float)j * 0.01f;
  const int id = ids[b * SEQ + j];
  const float c = cw[(size_t)id * NV + k];
  wtsT[(size_t)bk * SEQ + j] = c * score + (1.f - score);
}

// K6: ctxw[bk][i][j] = f16(ctx * wtsT[bk][j]). grid 32768, block 256
__global__ void k_ctx(const float* __restrict__ ctx, const float* __restrict__ wtsT,
                      u16* __restrict__ ctxw) {
  const size_t i = ((size_t)blockIdx.x * 256 + threadIdx.x) * 4;
  const float4 c = *(const float4*)(ctx + i);
  const size_t bk = i >> 20;           // / (SEQ*SEQ)
  const int j = (int)(i & (SEQ - 1));  // column within row
  const float4 wv = *(const float4*)(wtsT + bk * SEQ + j);
  *(uint2*)(ctxw + i) =
      make_uint2(pk2h(c.x * wv.x, c.y * wv.y), pk2h(c.z * wv.z, c.w * wv.w));
}

// K7: hidden partials. grid (6, 8, 8): x=d-tile, y=i-tile, z=b*4+g
// (4 senses/group; SEQ/32=32 ksteps per sense call — even, tail-safe)
__global__ __launch_bounds__(256) void k_hidden(const u16* __restrict__ ctxw,
                                                const u16* __restrict__ cT,
                                                float* __restrict__ part) {
  __shared__ __align__(16) u16 As[2 * 128 * 32];
  __shared__ __align__(16) u16 Bs[2 * 128 * 32];
  const int z = blockIdx.z;
  const int b = z >> 2, g = z & 3;
  const int i0 = blockIdx.y * 128, d0 = blockIdx.x * 128;
  const int t = threadIdx.x;
  f32x4 acc[4][4] = {};
  for (int kk = 0; kk < 4; ++kk) {
    const int sense = g * 4 + kk;
    const u16* A = ctxw + ((size_t)(b * NV + sense) * SEQ + i0) * SEQ;
    const u16* B = cT + ((size_t)(b * NV + sense) * DIM + d0) * SEQ;
    gemm_core<SEQ, SEQ>(A, B, SEQ / 32, As, Bs, acc, t);
    __syncthreads();  // tail reads done before next call restages buf0
  }
  const int lane = t & 63, w = t >> 6, wr = w >> 1, wc = w & 1;
  const int rg = lane >> 4, cl = lane & 15;
  float* P = part + ((size_t)(g * BSZ + b) * SEQ + i0) * DIM + d0;
#pragma unroll
  for (int m = 0; m < 4; ++m)
#pragma unroll
    for (int n = 0; n < 4; ++n)
#pragma unroll
      for (int r = 0; r < 4; ++r)
        P[(size_t)(wr * 64 + m * 16 + rg * 4 + r) * DIM + wc * 64 + n * 16 + cl] =
            acc[m][n][r];
}

// K8: hid = f16(sum_g part[g]). grid 1536, block 256
__global__ void k_reduce(const float* __restrict__ part, u16* __restrict__ hid) {
  const size_t i = ((size_t)blockIdx.x * 256 + threadIdx.x) * 4;
  const size_t NHID = (size_t)BSZ * SEQ * DIM;
  float4 s = {0.f, 0.f, 0.f, 0.f};
#pragma unroll
  for (int g = 0; g < 4; ++g) {
    const float4 p = *(const float4*)(part + (size_t)g * NHID + i);
    s.x += p.x; s.y += p.y; s.z += p.z; s.w += p.w;
  }
  *(uint2*)(hid + i) = make_uint2(pk2h(s.x, s.y), pk2h(s.z, s.w));
}

// K9: logits = hid @ Wb^T. 1D grid 6288 = 16 i-tiles x 393 v-tiles,
// XCD-swizzled (6288 % 8 == 0 -> simple swizzle bijective): each XCD gets a
// contiguous logical chunk so the 16 blocks sharing a Wb v-tile hit one L2.
__global__ __launch_bounds__(256) void k_logits(const u16* __restrict__ hid,
                                                const u16* __restrict__ Wb,
                                                float* __restrict__ out) {
  __shared__ __align__(16) u16 As[2 * 128 * 32];
  __shared__ __align__(16) u16 Bs[2 * 128 * 32];
  const int nwg = 16 * 393;
  const int bid = blockIdx.x;
  const int swz = (bid & 7) * (nwg / 8) + (bid >> 3);
  const int i0 = (swz & 15) * 128, v0 = (swz >> 4) * 128;
  const int t = threadIdx.x;
  const u16* A = hid + (size_t)i0 * DIM;
  const u16* B = Wb + (size_t)v0 * DIM;
  f32x4 acc[4][4] = {};
  gemm_core<DIM, DIM>(A, B, DIM / 32, As, Bs, acc, t);
  const int lane = t & 63, w = t >> 6, wr = w >> 1, wc = w & 1;
  const int rg = lane >> 4, cl = lane & 15;
#pragma unroll
  for (int m = 0; m < 4; ++m)
#pragma unroll
    for (int n = 0; n < 4; ++n) {
      const int vv = v0 + wc * 64 + n * 16 + cl;
      if (vv < VOC) {
#pragma unroll
        for (int r = 0; r < 4; ++r) {
          const int i = i0 + wr * 64 + m * 16 + rg * 4 + r;
          out[(size_t)i * VOC + vv] = acc[m][n][r];
        }
      }
    }
}

// ---------------------------------------------------------------------------
extern "C" void kernel_launch(void* const* d_in, const int* in_sizes, int n_in,
                              void* d_out, int out_size, void* d_ws, size_t ws_size,
                              hipStream_t stream) {
  const int* ids = (const int*)d_in[0];
  const float* content = (const float*)d_in[1];
  const float* ctx = (const float*)d_in[2];
  const float* W = (const float*)d_in[3];
  const float* cw = (const float*)d_in[4];
  float* out = (float*)d_out;
  char* ws = (char*)d_ws;

  // workspace layout (bytes, all 256-aligned); total 248,446,976
  u16* cbf  = (u16*)(ws);                  // 50,331,648  [32][S][D] f16
  u16* cT   = (u16*)(ws + 50331648);       // 50,331,648  [32][D][S] f16
  u16* Wb   = (u16*)(ws + 100663296);      // 77,266,944  [VOCP][D] f16
  u16* Wg   = (u16*)(ws + 177930240);      //  3,145,728  [B][S][D] f16
  u16* ctxw = (u16*)(ws + 181075968);      // 67,108,864  [32][S][S] f16
  float* sims = (float*)(ws + 248184832);  //    131,072  [32][S] f32
  float* wtsT = (float*)(ws + 248315904);  //    131,072  [32][S] f32
  // aliases (safe by dataflow: source buffer dead before alias first written)
  float* part = (float*)cbf;               // 25,165,824  [4][B][S][D] f32
  u16* hid = Wg;                           //  3,145,728  [B*S][D] f16

  k_prep_content<<<dim3(DIM / 32, SEQ / 32, BSZ * NV), dim3(32, 8), 0, stream>>>(
      content, cbf, cT);
  k_prep_w<<<VOCP, 192, 0, stream>>>(W, Wb);
  k_gather<<<dim3(SEQ, BSZ), 192, 0, stream>>>(ids, Wb, Wg);
  k_zero<<<128, 256, 0, stream>>>(sims, BSZ * NV * SEQ);
  k_sims<<<dim3(8, 8, BSZ * NV), 256, 0, stream>>>(cbf, Wg, sims);
  k_weights<<<dim3(4, BSZ * NV), 256, 0, stream>>>(sims, ids, cw, wtsT);
  k_ctx<<<32768, 256, 0, stream>>>(ctx, wtsT, ctxw);
  k_hidden<<<dim3(6, 8, 8), 256, 0, stream>>>(ctxw, cT, part);
  k_reduce<<<1536, 256, 0, stream>>>(part, hid);
  k_logits<<<16 * 393, 256, 0, stream>>>(hid, Wb, out);
}